// Round 11
// baseline (207.728 us; speedup 1.0000x reference)
//
#include <hip/hip_runtime.h>
#include <cstdint>

#define BB     4096
#define TT     96
#define NC     85
#define BLANKC 84
#define DD     64
#define ALPHA  0.05f
#define BT     (BB * TT)      // 393216
#define SLICE_F (NC * 17)     // 1445 floats per wave-private slice (pad 16->17)
#define GPB    4              // batch elements per fused block
#define PPB    (GPB * TT)     // 384 positions per block
#define NBLKF  (BB / GPB)     // 1024 fused blocks
#define NSS    12             // super-steps of 16 positions per wave-group

// ---------------------------------------------------------------------------
// Fused kernel: block = 4 batch elements (positions blk*384..+384).
//  Phase 1 (no barriers): wave-shuffle argmax. Wave w owns 48 rows; per row
//    lane l holds cols l and l+64 (-inf pad), 6-step __shfl_xor reduce with
//    first-index tie-break; lane0 -> pls[]. 2-group (4-row) load pipeline.
//    Feature super-steps 0..3 are issued in the PROLOGUE (16 scalar loads in
//    registers) so the feature stream overlaps this phase.
//  B1 -> mask phase (t<384): CTC mask from pls[t+1] (in-block), labm_w pack,
//    LDS histogram.  B2 -> dup phase (t<96): 6 label compares per 4-position
//    group, dup flag packed into bit30 of labm_w[4t].  B3 -> feature phase:
//    R10 pipeline, 4 rotating register buffers (fA..fD, 16 VGPRs), labels via
//    LDS uint4 broadcast reads; wave w owns dim-quad dq=w&3, PRIVATE slice
//    [85][17]; plain LDS RMW unless dup (wave-uniform atomic fallback).
//  Epilogue: slices -> updp[blk], hist -> hpartT[class][blk], |f|^2 -> lossp.
// LDS ~49.7 KB -> 3 blocks/CU (24 waves). NO global atomics.
// ---------------------------------------------------------------------------
__device__ inline void pload(const float* __restrict__ pb, int r0, int lane,
                             float* arr) {
#pragma unroll
    for (int rr = 0; rr < 4; ++rr) {
        const float* rp = pb + (size_t)(r0 + rr) * NC;
        arr[rr * 2]     = rp[lane];
        arr[rr * 2 + 1] = (lane < NC - 64) ? rp[64 + lane] : -3.4e38f;
    }
}

__device__ inline void preduce(int* __restrict__ pls, int r0, int lane,
                               const float* arr) {
#pragma unroll
    for (int rr = 0; rr < 4; ++rr) {
        float v; int bi;
        if (arr[rr * 2 + 1] > arr[rr * 2]) { v = arr[rr * 2 + 1]; bi = lane + 64; }
        else                               { v = arr[rr * 2];     bi = lane; }
#pragma unroll
        for (int off = 32; off; off >>= 1) {
            float ov = __shfl_xor(v, off);
            int   oi = __shfl_xor(bi, off);
            if (ov > v || (ov == v && oi < bi)) { v = ov; bi = oi; }
        }
        if (lane == 0) pls[r0 + rr] = bi;
    }
}

__global__ __launch_bounds__(512, 6) void k_fused(const float* __restrict__ preds,
                                                  const int* __restrict__ labels,
                                                  const float* __restrict__ feat,
                                                  float* __restrict__ updp,
                                                  int* __restrict__ hpartT,
                                                  float* __restrict__ lossp,
                                                  float* __restrict__ out) {
    __shared__ float sl[8 * SLICE_F];              // 46240 B
    __shared__ __align__(16) unsigned labm_w[PPB]; // 1536 B
    __shared__ int   pls[PPB];                     // 1536 B
    __shared__ int   h[NC];
    __shared__ float lred[8];

    int tid  = threadIdx.x;
    int blk  = blockIdx.x;
    int lane = tid & 63;
    int w    = tid >> 6;
    int dq   = w & 3;
    int wg   = w >> 2;
    int sub  = lane >> 4;
    int l16  = lane & 15;
    float* slice = sl + w * SLICE_F;

    // ---- prologue ----
    for (int i = tid; i < 8 * SLICE_F; i += 512) sl[i] = 0.f;
    if (tid < NC) h[tid] = 0;
    if (blk == 0 && tid == 500) out[0] = 0.f;
    int labreg = (tid < PPB) ? labels[blk * PPB + tid] : 0;

    const float* fbase = feat + (size_t)blk * PPB * DD + dq * 16 + l16;
    int p0 = wg * (NSS * 16);                      // 0 or 192
    int g0 = wg * (NSS * 4);                       // labm_w uint4 group base
    float fA0, fA1, fA2, fA3, fB0, fB1, fB2, fB3;
    float fC0, fC1, fC2, fC3, fD0, fD1, fD2, fD3;

#define ISSUE_F(P, f0, f1, f2, f3) do {                          \
    int _p = (P);                                                \
    f0 = fbase[(size_t)(_p + sub) * DD];                         \
    f1 = fbase[(size_t)(_p + 4 + sub) * DD];                     \
    f2 = fbase[(size_t)(_p + 8 + sub) * DD];                     \
    f3 = fbase[(size_t)(_p + 12 + sub) * DD];                    \
} while (0)

    ISSUE_F(p0,      fA0, fA1, fA2, fA3);
    ISSUE_F(p0 + 16, fB0, fB1, fB2, fB3);
    ISSUE_F(p0 + 32, fC0, fC1, fC2, fC3);
    ISSUE_F(p0 + 48, fD0, fD1, fD2, fD3);

    // ---- phase 1: shuffle argmax, 48 rows/wave, 2-group pipeline ----
    {
        const float* pb = preds + (size_t)blk * PPB * NC;
        int rb = w * 48;
        float av[8], bv[8];
        pload(pb, rb, lane, av);
        for (int g = 0; g < 12; g += 2) {
            pload(pb, rb + (g + 1) * 4, lane, bv);
            preduce(pls, rb + g * 4, lane, av);
            if (g + 2 < 12) pload(pb, rb + (g + 2) * 4, lane, av);
            preduce(pls, rb + (g + 1) * 4, lane, bv);
        }
    }
    __syncthreads();                               // B1: pls complete

    // ---- mask phase ----
    if (tid < PPB) {
        int p  = pls[tid];
        int lp = tid % TT;
        int m  = (p != BLANKC) && (lp == TT - 1 || p != pls[tid + 1]);
        labm_w[tid] = (unsigned)labreg | ((unsigned)m << 31);
        atomicAdd(&h[labreg], m);                  // LDS only
    }
    __syncthreads();                               // B2: labm_w complete

    // ---- dup phase: bit30 of word 0 per 4-position group ----
    if (tid < PPB / 4) {
        unsigned a0 = labm_w[tid * 4]     & 0x7fffffffu;
        unsigned a1 = labm_w[tid * 4 + 1] & 0x7fffffffu;
        unsigned a2 = labm_w[tid * 4 + 2] & 0x7fffffffu;
        unsigned a3 = labm_w[tid * 4 + 3] & 0x7fffffffu;
        bool dup = (a0 == a1) | (a0 == a2) | (a0 == a3) |
                   (a1 == a2) | (a1 == a3) | (a2 == a3);
        if (dup) labm_w[tid * 4] |= 0x40000000u;
    }
    __syncthreads();                               // B3: dup flags visible

    // ---- feature phase ----
    const uint4* labm4 = (const uint4*)labm_w;
    float lsum = 0.f;

#define SUBSTEP(GI, fc) do {                                     \
    uint4 lv = labm4[GI];                                        \
    bool dup = (lv.x >> 30) & 1u;                                \
    unsigned lw = (sub & 2) ? ((sub & 1) ? lv.w : lv.z)          \
                            : ((sub & 1) ? lv.y : lv.x);         \
    float m = (float)(lw >> 31);                                 \
    int  la = (int)(lw & 0x3fffffffu);                           \
    float c = m * (fc);                                          \
    lsum = fmaf(c, (fc), lsum);                                  \
    int a = la * 17 + l16;                                       \
    if (!dup) slice[a] += c;                                     \
    else      atomicAdd(&slice[a], c);                           \
} while (0)

#pragma unroll
    for (int ss = 0; ss < NSS; ss += 4) {
        SUBSTEP(g0 + ss * 4 + 0, fA0); SUBSTEP(g0 + ss * 4 + 1, fA1);
        SUBSTEP(g0 + ss * 4 + 2, fA2); SUBSTEP(g0 + ss * 4 + 3, fA3);
        if (ss + 4 < NSS) ISSUE_F(p0 + (ss + 4) * 16, fA0, fA1, fA2, fA3);
        SUBSTEP(g0 + (ss + 1) * 4 + 0, fB0); SUBSTEP(g0 + (ss + 1) * 4 + 1, fB1);
        SUBSTEP(g0 + (ss + 1) * 4 + 2, fB2); SUBSTEP(g0 + (ss + 1) * 4 + 3, fB3);
        if (ss + 5 < NSS) ISSUE_F(p0 + (ss + 5) * 16, fB0, fB1, fB2, fB3);
        SUBSTEP(g0 + (ss + 2) * 4 + 0, fC0); SUBSTEP(g0 + (ss + 2) * 4 + 1, fC1);
        SUBSTEP(g0 + (ss + 2) * 4 + 2, fC2); SUBSTEP(g0 + (ss + 2) * 4 + 3, fC3);
        if (ss + 6 < NSS) ISSUE_F(p0 + (ss + 6) * 16, fC0, fC1, fC2, fC3);
        SUBSTEP(g0 + (ss + 3) * 4 + 0, fD0); SUBSTEP(g0 + (ss + 3) * 4 + 1, fD1);
        SUBSTEP(g0 + (ss + 3) * 4 + 2, fD2); SUBSTEP(g0 + (ss + 3) * 4 + 3, fD3);
        if (ss + 7 < NSS) ISSUE_F(p0 + (ss + 7) * 16, fD0, fD1, fD2, fD3);
    }
#undef ISSUE_F
#undef SUBSTEP
    __syncthreads();                               // B4: all slices final

    // ---- epilogue ----
    float* myp = updp + (size_t)blk * (NC * DD);
    for (int i = tid; i < NC * DD; i += 512) {
        int r = i >> 6, d = i & 63;
        int qq = d >> 4, d16 = d & 15;
        myp[i] = sl[qq * SLICE_F + r * 17 + d16] +
                 sl[(qq + 4) * SLICE_F + r * 17 + d16];
    }
    if (tid < NC) hpartT[tid * NBLKF + blk] = h[tid];
#pragma unroll
    for (int off = 32; off; off >>= 1) lsum += __shfl_xor(lsum, off);
    if (lane == 0) lred[w] = lsum;
    __syncthreads();
    if (tid == 0) {
        float s = 0.f;
#pragma unroll
        for (int ww = 0; ww < 8; ++ww) s += lred[ww];
        lossp[blk] = s;
    }
}

// ---------------------------------------------------------------------------
// Kernel 2: grid NC*4+1. Block (j,q): counts[j] = coalesced sum of
// hpartT[j][0..NBLKF), then F over NBLKF partials for 16 dims, write centers,
// atomic-add 0.5*loss piece into out[0]. Last block reduces Sfeat.
// ---------------------------------------------------------------------------
__global__ __launch_bounds__(256) void k_reduce(const float* __restrict__ updp,
                                                const float* __restrict__ lossp,
                                                const float* __restrict__ centers,
                                                const int* __restrict__ hpartT,
                                                float* __restrict__ out) {
    __shared__ float sred[256];
    __shared__ float sr[4];
    __shared__ int   scnt;
    int tid = threadIdx.x;
    int bid = blockIdx.x;
    if (bid < NC * 4) {
        int j = bid >> 2, q = bid & 3;
        int cs = 0;
        for (int t = tid; t < NBLKF; t += 256) cs += hpartT[j * NBLKF + t];
#pragma unroll
        for (int off = 32; off; off >>= 1) cs += __shfl_xor(cs, off);
        int lane = tid & 63, wv = tid >> 6;
        if (lane == 0) ((int*)sred)[wv] = cs;
        __syncthreads();
        if (tid == 0)
            scnt = ((int*)sred)[0] + ((int*)sred)[1] +
                   ((int*)sred)[2] + ((int*)sred)[3];
        __syncthreads();
        float cnt = (float)scnt;
        int i = tid & 15;
        int c16 = tid >> 4;
        int per = NBLKF >> 4;                      // 64
        int col = j * DD + q * 16 + i;
        float s = 0.f;
        for (int b = c16 * per; b < (c16 + 1) * per; ++b)
            s += updp[(size_t)b * (NC * DD) + col];
        sred[tid] = s;
        __syncthreads();
        if (tid < 16) {
            float F = 0.f;
#pragma unroll
            for (int cc = 0; cc < 16; ++cc) F += sred[cc * 16 + i];
            float c   = centers[col];
            float scale = ALPHA / (1.f + cnt);
            out[1 + col] = c - scale * (cnt * c - F);
            float lp = cnt * c * c - 2.f * c * F;
#pragma unroll
            for (int off = 8; off; off >>= 1) lp += __shfl_xor(lp, off);
            if (i == 0) atomicAdd(&out[0], 0.5f * lp);
        }
    } else {
        float s = 0.f;
        for (int t = tid; t < NBLKF; t += 256) s += lossp[t];
#pragma unroll
        for (int off = 32; off; off >>= 1) s += __shfl_xor(s, off);
        int lane = tid & 63, wv = tid >> 6;
        if (lane == 0) sr[wv] = s;
        __syncthreads();
        if (tid == 0) atomicAdd(&out[0], 0.5f * (sr[0] + sr[1] + sr[2] + sr[3]));
    }
}

// ---------------------------------------------------------------------------
extern "C" void kernel_launch(void* const* d_in, const int* in_sizes, int n_in,
                              void* d_out, int out_size, void* d_ws, size_t ws_size,
                              hipStream_t stream) {
    const float* preds    = (const float*)d_in[0];
    const float* features = (const float*)d_in[1];
    const int*   labels   = (const int*)d_in[2];
    const float* centers  = (const float*)d_in[3];
    float* out = (float*)d_out;

    char* ws = (char*)d_ws;
    float* updp   = (float*)ws;                                  // 22.3 MB
    int*   hpartT = (int*)(ws + (size_t)NBLKF * NC * DD * 4);    // 348 KB
    float* lossp  = (float*)(ws + (size_t)NBLKF * NC * DD * 4
                                + (size_t)NC * NBLKF * 4);       // 4 KB

    k_fused<<<NBLKF, 512, 0, stream>>>(preds, labels, features,
                                       updp, hpartT, lossp, out);
    k_reduce<<<NC * 4 + 1, 256, 0, stream>>>(updp, lossp, centers, hpartT, out);
}

// Round 12
// 85.420 us; speedup vs baseline: 2.4318x; 2.4318x over previous
//
#include <hip/hip_runtime.h>
#include <cstdint>

#define BB     4096
#define TT     96
#define NC     85
#define BLANKC 84
#define DD     64
#define ALPHA  0.05f
#define BT     (BB * TT)      // 393216
#define SLICE_F (NC * 17)     // 1445 floats per wave-private slice (pad 16->17)
#define NF4    (TT * NC / 4)  // 2040 float4 per batch row

// ---------------------------------------------------------------------------
// Kernel 1: fused argmax + CTC mask + per-block histogram, WAVE-PRIVATE
// stage->scan (no block barrier between them, so waves de-phase and HBM
// stays fed). Block = one batch element (96 positions x 85 classes).
//  - wave w stages its own 12 positions: 255 contiguous float4 (4 coalesced
//    rounds) -> rows[12w*85 ..]; no barrier (same-wave LDS ordering).
//  - scan: lanes 0..47, lane = 4*r_local + q; quarter q of row 12w+r_local
//    scanned from LDS (stride-85: ~2-way bank aliasing = free), strict >
//    keeps first index.
//  - combine: 2-step __shfl_xor butterfly over the 4 quarter-lanes with
//    (value, lowest-col) tie-break; lane 4*r_local writes pls.
//  B1 -> mask phase (t<96): CTC mask from pls[t+1], labm pack, LDS histogram.
//  B2 -> hpartT[class][block] write (transposed, unconditional).
// NO global atomics. LDS ~34 KB -> 4 blocks/CU (32 waves).
// ---------------------------------------------------------------------------
__global__ __launch_bounds__(512) void k_amask(const float4* __restrict__ p4,
                                               const int* __restrict__ labels,
                                               unsigned* __restrict__ labm,
                                               int* __restrict__ hpartT,
                                               float* __restrict__ out) {
    __shared__ float rows[TT * NC];                // 32640 B
    __shared__ int   pls[TT];
    __shared__ int   h[NC];
    int tid  = threadIdx.x;
    int b    = blockIdx.x;
    int lane = tid & 63;
    int w    = tid >> 6;
    if (tid < NC) h[tid] = 0;
    if (b == 0 && tid == 480) out[0] = 0.f;
    int labreg = (tid < TT) ? labels[b * TT + tid] : 0;

    // ---- wave-private stage: 255 f4 = positions 12w..12w+12 ----
    {
        const float4* src = p4 + (size_t)b * NF4 + 255 * w;
        float4* dst = (float4*)(rows + (size_t)w * 12 * NC);
        float4 v0 = src[lane];
        float4 v1 = src[lane + 64];
        float4 v2 = src[lane + 128];
        float4 v3 = (lane < 63) ? src[lane + 192] : v2;
        dst[lane]       = v0;
        dst[lane + 64]  = v1;
        dst[lane + 128] = v2;
        if (lane < 63) dst[lane + 192] = v3;
    }
    // ---- wave-private scan (lanes 0..47): quarter q of row 12w+r ----
    {
        const int c0t[4] = {0, 22, 43, 64};
        const int c1t[4] = {22, 43, 64, 85};
        int r  = lane >> 2;
        int q  = lane & 3;
        float bv = -3.4e38f; int bc = 127;
        if (lane < 48) {
            const float* row = rows + (w * 12 + r) * NC;
            int c0 = c0t[q], c1 = c1t[q];
            bv = row[c0]; bc = c0;
            for (int c = c0 + 1; c < c1; ++c) {
                float v = row[c];
                if (v > bv) { bv = v; bc = c; }
            }
        }
#pragma unroll
        for (int m = 1; m <= 2; m <<= 1) {
            float ov = __shfl_xor(bv, m);
            int   oc = __shfl_xor(bc, m);
            if (ov > bv || (ov == bv && oc < bc)) { bv = ov; bc = oc; }
        }
        if (lane < 48 && (lane & 3) == 0) pls[w * 12 + r] = bc;
    }
    __syncthreads();                               // B1: pls complete
    // ---- mask + histogram ----
    if (tid < TT) {
        int p = pls[tid];
        int m = (p != BLANKC) && (tid == TT - 1 || p != pls[tid + 1]);
        labm[b * TT + tid] = (unsigned)labreg | ((unsigned)m << 31);
        atomicAdd(&h[labreg], m);                  // LDS only
    }
    __syncthreads();                               // B2: h complete
    if (tid < NC) hpartT[tid * BB + b] = h[tid];   // unconditional, transposed
}

// ---------------------------------------------------------------------------
// Kernel 2: masked feature segment-sum with an 8-load-deep register pipeline
// (R10 verbatim). 8 waves/block; wave w owns dim-quad dq=w&3 with PRIVATE
// slice [85][17]. Super-step = 16 positions, double-buffered named registers.
// ---------------------------------------------------------------------------
__global__ __launch_bounds__(512, 6) void k_main(const float* __restrict__ feat,
                                                 const unsigned* __restrict__ labm,
                                                 float* __restrict__ updp,
                                                 float* __restrict__ lossp, int nb) {
    __shared__ float sl[8 * SLICE_F];              // 46240 B
    __shared__ float lred[8];
    int tid = threadIdx.x;
    for (int i = tid; i < 8 * SLICE_F; i += 512) sl[i] = 0.f;
    __syncthreads();

    int lane = tid & 63;
    int w    = tid >> 6;
    int dq   = w & 3;
    int wg   = w >> 2;
    int sub  = lane >> 4;
    int l16  = lane & 15;
    float* slice = sl + w * SLICE_F;

    int ppc = BT / (nb * 2);                       // 256 when nb=768
    int p0  = (blockIdx.x * 2 + wg) * ppc;
    int nss = ppc / 16;
    const float* fbase = feat + dq * 16 + l16;

    float lsum = 0.f;
    float fA0, fA1, fA2, fA3, fB0, fB1, fB2, fB3;
    uint4 lA0, lA1, lA2, lA3, lB0, lB1, lB2, lB3;

#define ISSUE(P, f0, f1, f2, f3, q0, q1, q2, q3) do {            \
    int _p = (P);                                                \
    q0 = *(const uint4*)(labm + _p);                             \
    q1 = *(const uint4*)(labm + _p + 4);                         \
    q2 = *(const uint4*)(labm + _p + 8);                         \
    q3 = *(const uint4*)(labm + _p + 12);                        \
    f0 = fbase[(size_t)(_p + sub) * DD];                         \
    f1 = fbase[(size_t)(_p + 4 + sub) * DD];                     \
    f2 = fbase[(size_t)(_p + 8 + sub) * DD];                     \
    f3 = fbase[(size_t)(_p + 12 + sub) * DD];                    \
} while (0)

#define SUBSTEP(lv, fc) do {                                     \
    unsigned a0 = lv.x & 0x7fffffffu, a1 = lv.y & 0x7fffffffu,   \
             a2 = lv.z & 0x7fffffffu, a3 = lv.w & 0x7fffffffu;   \
    bool dup = (a0 == a1) | (a0 == a2) | (a0 == a3) |            \
               (a1 == a2) | (a1 == a3) | (a2 == a3);             \
    unsigned lw = (sub & 2) ? ((sub & 1) ? lv.w : lv.z)          \
                            : ((sub & 1) ? lv.y : lv.x);         \
    float m = (float)(lw >> 31);                                 \
    int  la = (int)(lw & 0x7fffffffu);                           \
    float c = m * (fc);                                          \
    lsum = fmaf(c, (fc), lsum);                                  \
    int a = la * 17 + l16;                                       \
    if (!dup) slice[a] += c;                                     \
    else      atomicAdd(&slice[a], c);                           \
} while (0)

    ISSUE(p0, fA0, fA1, fA2, fA3, lA0, lA1, lA2, lA3);
    for (int ss = 0; ss < nss; ss += 2) {
        if (ss + 1 < nss)
            ISSUE(p0 + (ss + 1) * 16, fB0, fB1, fB2, fB3, lB0, lB1, lB2, lB3);
        SUBSTEP(lA0, fA0); SUBSTEP(lA1, fA1);
        SUBSTEP(lA2, fA2); SUBSTEP(lA3, fA3);
        if (ss + 1 < nss) {
            if (ss + 2 < nss)
                ISSUE(p0 + (ss + 2) * 16, fA0, fA1, fA2, fA3, lA0, lA1, lA2, lA3);
            SUBSTEP(lB0, fB0); SUBSTEP(lB1, fB1);
            SUBSTEP(lB2, fB2); SUBSTEP(lB3, fB3);
        }
    }
#undef ISSUE
#undef SUBSTEP
    __syncthreads();

    float* myp = updp + (size_t)blockIdx.x * (NC * DD);
    for (int i = tid; i < NC * DD; i += 512) {
        int r = i >> 6, d = i & 63;
        int qq = d >> 4, d16 = d & 15;
        myp[i] = sl[qq * SLICE_F + r * 17 + d16] +
                 sl[(qq + 4) * SLICE_F + r * 17 + d16];
    }
#pragma unroll
    for (int off = 32; off; off >>= 1) lsum += __shfl_xor(lsum, off);
    if (lane == 0) lred[w] = lsum;
    __syncthreads();
    if (tid == 0) {
        float s = 0.f;
#pragma unroll
        for (int ww = 0; ww < 8; ++ww) s += lred[ww];
        lossp[blockIdx.x] = s;
    }
}

// ---------------------------------------------------------------------------
// Kernel 3: grid NC*4+1 (R10 verbatim). Block (j,q): counts[j] from hpartT,
// F over nb partials for 16 dims, write centers, atomic 0.5*loss into out[0].
// ---------------------------------------------------------------------------
__global__ __launch_bounds__(256) void k_reduce(const float* __restrict__ updp,
                                                const float* __restrict__ lossp,
                                                const float* __restrict__ centers,
                                                const int* __restrict__ hpartT,
                                                float* __restrict__ out, int nb) {
    __shared__ float sred[256];
    __shared__ float sr[4];
    __shared__ int   scnt;
    int tid = threadIdx.x;
    int bid = blockIdx.x;
    if (bid < NC * 4) {
        int j = bid >> 2, q = bid & 3;
        int cs = 0;
        for (int t = tid; t < BB; t += 256) cs += hpartT[j * BB + t];
#pragma unroll
        for (int off = 32; off; off >>= 1) cs += __shfl_xor(cs, off);
        int lane = tid & 63, wv = tid >> 6;
        if (lane == 0) ((int*)sred)[wv] = cs;
        __syncthreads();
        if (tid == 0)
            scnt = ((int*)sred)[0] + ((int*)sred)[1] +
                   ((int*)sred)[2] + ((int*)sred)[3];
        __syncthreads();
        float cnt = (float)scnt;
        int i = tid & 15;
        int c16 = tid >> 4;
        int per = nb >> 4;
        int col = j * DD + q * 16 + i;
        float s = 0.f;
        for (int b = c16 * per; b < (c16 + 1) * per; ++b)
            s += updp[(size_t)b * (NC * DD) + col];
        sred[tid] = s;
        __syncthreads();
        if (tid < 16) {
            float F = 0.f;
#pragma unroll
            for (int cc = 0; cc < 16; ++cc) F += sred[cc * 16 + i];
            float c   = centers[col];
            float scale = ALPHA / (1.f + cnt);
            out[1 + col] = c - scale * (cnt * c - F);
            float lp = cnt * c * c - 2.f * c * F;
#pragma unroll
            for (int off = 8; off; off >>= 1) lp += __shfl_xor(lp, off);
            if (i == 0) atomicAdd(&out[0], 0.5f * lp);
        }
    } else {
        float s = 0.f;
        for (int t = tid; t < nb; t += 256) s += lossp[t];
#pragma unroll
        for (int off = 32; off; off >>= 1) s += __shfl_xor(s, off);
        int lane = tid & 63, wv = tid >> 6;
        if (lane == 0) sr[wv] = s;
        __syncthreads();
        if (tid == 0) atomicAdd(&out[0], 0.5f * (sr[0] + sr[1] + sr[2] + sr[3]));
    }
}

// ---------------------------------------------------------------------------
extern "C" void kernel_launch(void* const* d_in, const int* in_sizes, int n_in,
                              void* d_out, int out_size, void* d_ws, size_t ws_size,
                              hipStream_t stream) {
    const float* preds    = (const float*)d_in[0];
    const float* features = (const float*)d_in[1];
    const int*   labels   = (const int*)d_in[2];
    const float* centers  = (const float*)d_in[3];
    float* out = (float*)d_out;

    char* ws = (char*)d_ws;
    unsigned* labm = (unsigned*)ws;                             // BT words (1.5 MB)
    int* hpartT    = (int*)(ws + 4 * (size_t)BT);               // NC*BB ints (1.4 MB)
    size_t off0 = 4 * (size_t)BT + (size_t)NC * BB * 4 + 512;

    int nb = 768;
    while (nb > 16 && off0 + (size_t)nb * 4 + 512 +
                      (size_t)nb * NC * DD * 4 > ws_size)
        nb >>= 1;
    float* lossp = (float*)(ws + off0);                         // nb floats
    float* updp  = (float*)(ws + off0 + (size_t)nb * 4 + 512);

    k_amask<<<BB, 512, 0, stream>>>((const float4*)preds, labels, labm,
                                    hpartT, out);
    k_main<<<nb, 512, 0, stream>>>(features, labm, updp, lossp, nb);
    k_reduce<<<NC * 4 + 1, 256, 0, stream>>>(updp, lossp, centers, hpartT,
                                             out, nb);
}

// Round 13
// 82.703 us; speedup vs baseline: 2.5117x; 1.0328x over previous
//
#include <hip/hip_runtime.h>
#include <cstdint>

#define BB     4096
#define TT     96
#define NC     85
#define BLANKC 84
#define DD     64
#define ALPHA  0.05f
#define BT     (BB * TT)      // 393216
#define SLICE_F (NC * 17)     // 1445 floats per wave-private slice (pad 16->17)
#define NF4    (TT * NC / 4)  // 2040 float4 per batch row
#define RPBA   4              // batch rows per k_amask block
#define NBA    (BB / RPBA)    // 1024 amask blocks
#define NBM    512            // k_main blocks

// ---------------------------------------------------------------------------
// Kernel 1: fused argmax + CTC mask + histogram, 4 rows/block to amortize the
// per-block tail (barrier + mask + hist + hpartT write) that cost ~6-7 us at
// 1 row/block. Wave w owns positions 12w..12w+11 of each row; 4-iteration
// loop with 2-deep register pipeline: commit cur 4xfloat4 -> wave-private LDS
// (no barrier: same-wave LDS ordering), issue next row's loads, scan cur
// (lanes 0..47 quarter-scan stride-85, 2-step shuffle combine, lowest-col
// tie-break). Then ONE mask phase (384 thr) + histogram + hpartT[class][blk].
// ---------------------------------------------------------------------------
__global__ __launch_bounds__(512) void k_amask(const float4* __restrict__ p4,
                                               const int* __restrict__ labels,
                                               unsigned* __restrict__ labm,
                                               int* __restrict__ hpartT,
                                               float* __restrict__ out) {
    __shared__ float rows[8][12 * NC];             // 8 x 1020 floats = 32640 B
    __shared__ int   pls[RPBA * TT + 1];
    __shared__ int   h[NC];
    int tid  = threadIdx.x;
    int blk  = blockIdx.x;
    int lane = tid & 63;
    int w    = tid >> 6;
    if (tid < NC) h[tid] = 0;
    if (blk == 0 && tid == 480) out[0] = 0.f;
    int labreg = (tid < RPBA * TT) ? labels[blk * RPBA * TT + tid] : 0;

    // prologue: issue row 0 chunk (255 f4 = positions 12w..12w+11)
    const float4* src = p4 + (size_t)(blk * RPBA) * NF4 + 255 * w;
    float4 v0 = src[lane];
    float4 v1 = src[lane + 64];
    float4 v2 = src[lane + 128];
    float4 v3 = src[min(lane + 192, 254)];

    const int c0t[4] = {0, 22, 43, 64};
    const int c1t[4] = {22, 43, 64, 85};

    for (int i = 0; i < RPBA; ++i) {
        // commit current regs -> wave LDS
        float4* dst = (float4*)rows[w];
        dst[lane]       = v0;
        dst[lane + 64]  = v1;
        dst[lane + 128] = v2;
        if (lane < 63) dst[lane + 192] = v3;
        // issue next row's loads (overlaps the scan below)
        if (i + 1 < RPBA) {
            const float4* s2 = p4 + (size_t)(blk * RPBA + i + 1) * NF4 + 255 * w;
            v0 = s2[lane];
            v1 = s2[lane + 64];
            v2 = s2[lane + 128];
            v3 = s2[min(lane + 192, 254)];
        }
        // wave-private scan: lane = 4*r + q, quarter q of local row r (0..11)
        int r = lane >> 2, q = lane & 3;
        float bv = -3.4e38f; int bc = 127;
        if (lane < 48) {
            const float* row = rows[w] + r * NC;
            int c0 = c0t[q], c1 = c1t[q];
            bv = row[c0]; bc = c0;
            for (int c = c0 + 1; c < c1; ++c) {
                float v = row[c];
                if (v > bv) { bv = v; bc = c; }
            }
        }
#pragma unroll
        for (int m = 1; m <= 2; m <<= 1) {
            float ov = __shfl_xor(bv, m);
            int   oc = __shfl_xor(bc, m);
            if (ov > bv || (ov == bv && oc < bc)) { bv = ov; bc = oc; }
        }
        if (lane < 48 && (lane & 3) == 0) pls[i * TT + w * 12 + r] = bc;
    }
    __syncthreads();                               // B1: all pls complete
    // mask + labm pack + histogram (384 threads)
    if (tid < RPBA * TT) {
        int p  = pls[tid];
        int lp = tid % TT;
        int m  = (p != BLANKC) && (lp == TT - 1 || p != pls[tid + 1]);
        labm[blk * RPBA * TT + tid] = (unsigned)labreg | ((unsigned)m << 31);
        atomicAdd(&h[labreg], m);                  // LDS only
    }
    __syncthreads();                               // B2: h complete
    if (tid < NC) hpartT[tid * NBA + blk] = h[tid];
}

// ---------------------------------------------------------------------------
// Kernel 2: masked feature segment-sum (R10 structure, nb=512). 8 waves/blk;
// wave w owns dim-quad dq=w&3 with PRIVATE slice [85][17]. Super-step = 16
// positions, double-buffered named registers (8 loads in flight).
// ---------------------------------------------------------------------------
__global__ __launch_bounds__(512, 6) void k_main(const float* __restrict__ feat,
                                                 const unsigned* __restrict__ labm,
                                                 float* __restrict__ updp,
                                                 float* __restrict__ lossp) {
    __shared__ float sl[8 * SLICE_F];              // 46240 B
    __shared__ float lred[8];
    int tid = threadIdx.x;
    for (int i = tid; i < 8 * SLICE_F; i += 512) sl[i] = 0.f;
    __syncthreads();

    int lane = tid & 63;
    int w    = tid >> 6;
    int dq   = w & 3;
    int wg   = w >> 2;
    int sub  = lane >> 4;
    int l16  = lane & 15;
    float* slice = sl + w * SLICE_F;

    const int ppc = BT / (NBM * 2);                // 384
    const int nss = ppc / 16;                      // 24
    int p0  = (blockIdx.x * 2 + wg) * ppc;
    const float* fbase = feat + dq * 16 + l16;

    float lsum = 0.f;
    float fA0, fA1, fA2, fA3, fB0, fB1, fB2, fB3;
    uint4 lA0, lA1, lA2, lA3, lB0, lB1, lB2, lB3;

#define ISSUE(P, f0, f1, f2, f3, q0, q1, q2, q3) do {            \
    int _p = (P);                                                \
    q0 = *(const uint4*)(labm + _p);                             \
    q1 = *(const uint4*)(labm + _p + 4);                         \
    q2 = *(const uint4*)(labm + _p + 8);                         \
    q3 = *(const uint4*)(labm + _p + 12);                        \
    f0 = fbase[(size_t)(_p + sub) * DD];                         \
    f1 = fbase[(size_t)(_p + 4 + sub) * DD];                     \
    f2 = fbase[(size_t)(_p + 8 + sub) * DD];                     \
    f3 = fbase[(size_t)(_p + 12 + sub) * DD];                    \
} while (0)

#define SUBSTEP(lv, fc) do {                                     \
    unsigned a0 = lv.x & 0x7fffffffu, a1 = lv.y & 0x7fffffffu,   \
             a2 = lv.z & 0x7fffffffu, a3 = lv.w & 0x7fffffffu;   \
    bool dup = (a0 == a1) | (a0 == a2) | (a0 == a3) |            \
               (a1 == a2) | (a1 == a3) | (a2 == a3);             \
    unsigned lw = (sub & 2) ? ((sub & 1) ? lv.w : lv.z)          \
                            : ((sub & 1) ? lv.y : lv.x);         \
    float m = (float)(lw >> 31);                                 \
    int  la = (int)(lw & 0x7fffffffu);                           \
    float c = m * (fc);                                          \
    lsum = fmaf(c, (fc), lsum);                                  \
    int a = la * 17 + l16;                                       \
    if (!dup) slice[a] += c;                                     \
    else      atomicAdd(&slice[a], c);                           \
} while (0)

    ISSUE(p0, fA0, fA1, fA2, fA3, lA0, lA1, lA2, lA3);
    for (int ss = 0; ss < nss; ss += 2) {
        if (ss + 1 < nss)
            ISSUE(p0 + (ss + 1) * 16, fB0, fB1, fB2, fB3, lB0, lB1, lB2, lB3);
        SUBSTEP(lA0, fA0); SUBSTEP(lA1, fA1);
        SUBSTEP(lA2, fA2); SUBSTEP(lA3, fA3);
        if (ss + 1 < nss) {
            if (ss + 2 < nss)
                ISSUE(p0 + (ss + 2) * 16, fA0, fA1, fA2, fA3, lA0, lA1, lA2, lA3);
            SUBSTEP(lB0, fB0); SUBSTEP(lB1, fB1);
            SUBSTEP(lB2, fB2); SUBSTEP(lB3, fB3);
        }
    }
#undef ISSUE
#undef SUBSTEP
    __syncthreads();

    float* myp = updp + (size_t)blockIdx.x * (NC * DD);
    for (int i = tid; i < NC * DD; i += 512) {
        int r = i >> 6, d = i & 63;
        int qq = d >> 4, d16 = d & 15;
        myp[i] = sl[qq * SLICE_F + r * 17 + d16] +
                 sl[(qq + 4) * SLICE_F + r * 17 + d16];
    }
#pragma unroll
    for (int off = 32; off; off >>= 1) lsum += __shfl_xor(lsum, off);
    if (lane == 0) lred[w] = lsum;
    __syncthreads();
    if (tid == 0) {
        float s = 0.f;
#pragma unroll
        for (int ww = 0; ww < 8; ++ww) s += lred[ww];
        lossp[blockIdx.x] = s;
    }
}

// ---------------------------------------------------------------------------
// Kernel 3: grid NC*4+1. Block (j,q): counts[j] from hpartT[j][0..NBA),
// F over NBM partials for 16 dims, write centers, atomic 0.5*loss -> out[0].
// ---------------------------------------------------------------------------
__global__ __launch_bounds__(256) void k_reduce(const float* __restrict__ updp,
                                                const float* __restrict__ lossp,
                                                const float* __restrict__ centers,
                                                const int* __restrict__ hpartT,
                                                float* __restrict__ out) {
    __shared__ float sred[256];
    __shared__ float sr[4];
    __shared__ int   scnt;
    int tid = threadIdx.x;
    int bid = blockIdx.x;
    if (bid < NC * 4) {
        int j = bid >> 2, q = bid & 3;
        int cs = 0;
        for (int t = tid; t < NBA; t += 256) cs += hpartT[j * NBA + t];
#pragma unroll
        for (int off = 32; off; off >>= 1) cs += __shfl_xor(cs, off);
        int lane = tid & 63, wv = tid >> 6;
        if (lane == 0) ((int*)sred)[wv] = cs;
        __syncthreads();
        if (tid == 0)
            scnt = ((int*)sred)[0] + ((int*)sred)[1] +
                   ((int*)sred)[2] + ((int*)sred)[3];
        __syncthreads();
        float cnt = (float)scnt;
        int i = tid & 15;
        int c16 = tid >> 4;
        const int per = NBM >> 4;                  // 32
        int col = j * DD + q * 16 + i;
        float s = 0.f;
        for (int b = c16 * per; b < (c16 + 1) * per; ++b)
            s += updp[(size_t)b * (NC * DD) + col];
        sred[tid] = s;
        __syncthreads();
        if (tid < 16) {
            float F = 0.f;
#pragma unroll
            for (int cc = 0; cc < 16; ++cc) F += sred[cc * 16 + i];
            float c   = centers[col];
            float scale = ALPHA / (1.f + cnt);
            out[1 + col] = c - scale * (cnt * c - F);
            float lp = cnt * c * c - 2.f * c * F;
#pragma unroll
            for (int off = 8; off; off >>= 1) lp += __shfl_xor(lp, off);
            if (i == 0) atomicAdd(&out[0], 0.5f * lp);
        }
    } else {
        float s = 0.f;
        for (int t = tid; t < NBM; t += 256) s += lossp[t];
#pragma unroll
        for (int off = 32; off; off >>= 1) s += __shfl_xor(s, off);
        int lane = tid & 63, wv = tid >> 6;
        if (lane == 0) sr[wv] = s;
        __syncthreads();
        if (tid == 0) atomicAdd(&out[0], 0.5f * (sr[0] + sr[1] + sr[2] + sr[3]));
    }
}

// ---------------------------------------------------------------------------
extern "C" void kernel_launch(void* const* d_in, const int* in_sizes, int n_in,
                              void* d_out, int out_size, void* d_ws, size_t ws_size,
                              hipStream_t stream) {
    const float* preds    = (const float*)d_in[0];
    const float* features = (const float*)d_in[1];
    const int*   labels   = (const int*)d_in[2];
    const float* centers  = (const float*)d_in[3];
    float* out = (float*)d_out;

    char* ws = (char*)d_ws;
    unsigned* labm = (unsigned*)ws;                             // BT words (1.5 MB)
    int* hpartT    = (int*)(ws + 4 * (size_t)BT);               // NC*NBA ints (348 KB)
    size_t off0 = 4 * (size_t)BT + (size_t)NC * NBA * 4 + 512;
    float* lossp = (float*)(ws + off0);                         // NBM floats
    float* updp  = (float*)(ws + off0 + (size_t)NBM * 4 + 512); // 11.1 MB

    k_amask<<<NBA, 512, 0, stream>>>((const float4*)preds, labels, labm,
                                     hpartT, out);
    k_main<<<NBM, 512, 0, stream>>>(features, labm, updp, lossp);
    k_reduce<<<NC * 4 + 1, 256, 0, stream>>>(updp, lossp, centers, hpartT, out);
}